// Round 2
// baseline (1662.306 us; speedup 1.0000x reference)
//
#include <hip/hip_runtime.h>
#include <math.h>

#define T 256
#define E 256
#define H 1024
#define I_DIM 256
#define CAP 256      // max tokens per expert (worst case = T)

// ---------------- K1: logits + shared expert (also zeroes cnt, writes out) ----
// One block per token. Thread j owns expert j (logits) / intermediate col j
// (shared gate/up) / output cols j, j+256, j+512, j+768 (shared down).
// out = shared-expert result (plain store) -- replaces the old zero-init;
// routed experts accumulate on top via atomics in k3.
__global__ __launch_bounds__(256) void k1_logits_shared(
    const float* __restrict__ x, const float* __restrict__ gw,
    const float* __restrict__ swg, const float* __restrict__ swu,
    const float* __restrict__ swd,
    float* __restrict__ logits, int* __restrict__ cnt, float* __restrict__ out)
{
    const int t = blockIdx.x, j = threadIdx.x;
    __shared__ __align__(16) float xs[H];
    __shared__ float act[I_DIM];
#pragma unroll
    for (int k = 0; k < 4; ++k) xs[k * 256 + j] = x[t * H + k * 256 + j];
    if (t == 0) cnt[j] = 0;
    __syncthreads();

    // ---- logits: identical code/numerics to previous k1 ----
    const float4* w4 = (const float4*)(gw + (size_t)j * H);
    const float4* x4 = (const float4*)xs;
    float acc = 0.f;
#pragma unroll 8
    for (int h = 0; h < H / 4; ++h) {
        float4 w = w4[h];
        float4 v = x4[h];
        acc = fmaf(w.x, v.x, acc);
        acc = fmaf(w.y, v.y, acc);
        acc = fmaf(w.z, v.z, acc);
        acc = fmaf(w.w, v.w, acc);
    }
    logits[t * E + j] = acc;

    // ---- shared expert gate/up (ascending h, same order as before) ----
    float g = 0.f, uu = 0.f;
#pragma unroll 8
    for (int h = 0; h < H; ++h) {
        float xv = xs[h];
        g  = fmaf(xv, swg[h * I_DIM + j], g);
        uu = fmaf(xv, swu[h * I_DIM + j], uu);
    }
    act[j] = g / (1.f + __expf(-g)) * uu;
    __syncthreads();

    // ---- shared down (ascending i, same order as before) ----
    float o0 = 0.f, o1 = 0.f, o2 = 0.f, o3 = 0.f;
#pragma unroll 4
    for (int i = 0; i < I_DIM; ++i) {
        float a = act[i];
        const float* wr = swd + (size_t)i * H;
        o0 = fmaf(a, wr[j], o0);
        o1 = fmaf(a, wr[256 + j], o1);
        o2 = fmaf(a, wr[512 + j], o2);
        o3 = fmaf(a, wr[768 + j], o3);
    }
    out[(size_t)t * H + j]       = o0;
    out[(size_t)t * H + 256 + j] = o1;
    out[(size_t)t * H + 512 + j] = o2;
    out[(size_t)t * H + 768 + j] = o3;
}

// ---------------- K2: routing, one wave per token (unchanged) ----------------
__global__ __launch_bounds__(64) void k2_route(
    const float* __restrict__ logits, const float* __restrict__ e_bias,
    int* __restrict__ cnt, int* __restrict__ tok, float* __restrict__ wt)
{
    const int t = blockIdx.x;
    const int lane = threadIdx.x;   // 0..63, covers experts lane*4 .. lane*4+3

    float s[4], sc[4];
#pragma unroll
    for (int q = 0; q < 4; ++q) {
        int e = lane * 4 + q;
        float l = logits[t * E + e];
        float sig = 1.f / (1.f + expf(-l));
        s[q] = sig;                 // raw score (for weights)
        sc[q] = sig + e_bias[e];    // corrected score (for selection)
    }

    float m01 = fmaxf(sc[0], sc[1]), n01 = fminf(sc[0], sc[1]);
    float m23 = fmaxf(sc[2], sc[3]), n23 = fminf(sc[2], sc[3]);
    float a1 = fmaxf(m01, m23);
    float a2 = fmaxf(fminf(m01, m23), fmaxf(n01, n23));
#pragma unroll
    for (int off = 1; off < 8; off <<= 1) {
        float b1 = __shfl_xor(a1, off);
        float b2 = __shfl_xor(a2, off);
        float na1 = fmaxf(a1, b1);
        float na2 = fmaxf(fminf(a1, b1), fmaxf(a2, b2));
        a1 = na1; a2 = na2;
    }
    float gs = a1 + a2;   // group score = sum of top-2

    __shared__ float gsc[8];
    if ((lane & 7) == 0) gsc[lane >> 3] = gs;
    __syncthreads();

    float lg[8];
#pragma unroll
    for (int g = 0; g < 8; ++g) lg[g] = gsc[g];
    unsigned gmask = 0;
#pragma unroll
    for (int k = 0; k < 4; ++k) {
        float best = -__builtin_inff(); int bi = 0;
#pragma unroll
        for (int g = 0; g < 8; ++g) {
            bool take = !((gmask >> g) & 1u) && (lg[g] > best);
            if (take) { best = lg[g]; bi = g; }
        }
        gmask |= 1u << bi;
    }

    bool gon = (gmask >> (lane >> 3)) & 1u;
    float masked[4];
#pragma unroll
    for (int q = 0; q < 4; ++q) masked[q] = gon ? sc[q] : -__builtin_inff();

    int sel[8]; float selw[8]; float wsum = 0.f;
#pragma unroll
    for (int k = 0; k < 8; ++k) {
        float v = masked[0]; int qi = 0;
#pragma unroll
        for (int q = 1; q < 4; ++q) { if (masked[q] > v) { v = masked[q]; qi = q; } }
        int idx = lane * 4 + qi;
#pragma unroll
        for (int off = 1; off < 64; off <<= 1) {
            float ov = __shfl_xor(v, off);
            int   oi = __shfl_xor(idx, off);
            if (ov > v || (ov == v && oi < idx)) { v = ov; idx = oi; }
        }
        float rawv = s[idx & 3];
        rawv = __shfl(rawv, idx >> 2);
        sel[k] = idx; selw[k] = rawv; wsum += rawv;
        if ((idx >> 2) == lane) masked[idx & 3] = -__builtin_inff();
    }
    float scale = 2.5f / (wsum + 1e-20f);

#pragma unroll
    for (int k = 0; k < 8; ++k) {
        if (lane == k) {
            int e = sel[k];
            int pos = atomicAdd(&cnt[e], 1);
            tok[e * CAP + pos] = t;
            wt[e * CAP + pos] = selw[k] * scale;
        }
    }
}

// ---------------- K3: routed experts, ping-pong prefetch pipeline -------------
// Grid = 512: block b -> expert e = b&255, role p = b>>8.
//   p=0 handles tokens [0,16); p=1 (rare) handles [16,32),[32,48),... in-block.
// The p=1 companion lands on the same XCD (b%8 preserved) so its weight stream
// shares L2 with the p=0 block -> no serial 2nd pass for n>16 experts.
// All weight loads are double-buffered 16-deep (8-16 KB in flight per wave)
// so the ~900-cycle HBM latency hides under each chunk's ~1024 FMA cycles.
__global__ __launch_bounds__(256, 1) void k3_experts(
    const float* __restrict__ x,
    const float* __restrict__ w_gate, const float* __restrict__ w_up,
    const float* __restrict__ w_down,
    const int* __restrict__ cnt, const int* __restrict__ tok,
    const float* __restrict__ wt, float* __restrict__ out)
{
    const int e = blockIdx.x & 255;
    const int p = blockIdx.x >> 8;
    const int j = threadIdx.x;
    const int n = cnt[e];
    if (p * 16 >= n) return;

    __shared__ __align__(16) float smem[16 * 256];  // x tile, then activations
    __shared__ int   stok[16];
    __shared__ float swt_s[16];

    const float* wg = w_gate + (size_t)e * H * I_DIM;
    const float* wu = w_up   + (size_t)e * H * I_DIM;
    const float* wd = w_down + (size_t)e * I_DIM * H;

    for (int base = p * 16; base < n; base += 16) {
        const int nn = min(16, n - base);
        if (j < 16) {
            int tg = base + j;
            bool valid = tg < n;
            stok[j]  = valid ? tok[e * CAP + tg] : tok[e * CAP + base];
            swt_s[j] = valid ? wt[e * CAP + tg] : 0.f;
        }

        // ---- gate/up with ping-pong prefetch ----
        float h1[16], h3[16];
#pragma unroll
        for (int t2 = 0; t2 < 16; ++t2) { h1[t2] = 0.f; h3[t2] = 0.f; }

        float wA[16], wB[16], wC[16], wD[16];
#pragma unroll
        for (int u = 0; u < 16; ++u) {          // prefetch chunk h=0..15
            wA[u] = wg[(size_t)u * I_DIM + j];
            wB[u] = wu[(size_t)u * I_DIM + j];
        }

        for (int h0 = 0; h0 < H; h0 += 256) {
            __syncthreads();   // stok ready / previous tile consumed
            {   // stage x tile [16][256], vectorized (thread -> token j>>4, 64B span)
                const int t2 = j >> 4, c0 = (j & 15) * 16;
                const float4* src = (const float4*)(x + (size_t)stok[t2] * H + h0 + c0);
                float4* dst = (float4*)&smem[t2 * 256 + c0];
                dst[0] = src[0]; dst[1] = src[1]; dst[2] = src[2]; dst[3] = src[3];
            }
            __syncthreads();
#pragma unroll 1
            for (int hh = 0; hh < 256; hh += 32) {
                const int hB = h0 + hh + 16;
                int hN = h0 + hh + 32;
                if (hN >= H) hN = 0;            // harmless clamp, values unused
                // prefetch odd chunk (in flight during even-chunk FMA)
#pragma unroll
                for (int u = 0; u < 16; ++u) {
                    wC[u] = wg[(size_t)(hB + u) * I_DIM + j];
                    wD[u] = wu[(size_t)(hB + u) * I_DIM + j];
                }
                // FMA even chunk (ascending h: identical rounding to baseline)
#pragma unroll
                for (int t2 = 0; t2 < 16; ++t2) {
                    float xv[16];
                    *(float4*)&xv[0]  = *(const float4*)&smem[t2 * 256 + hh];
                    *(float4*)&xv[4]  = *(const float4*)&smem[t2 * 256 + hh + 4];
                    *(float4*)&xv[8]  = *(const float4*)&smem[t2 * 256 + hh + 8];
                    *(float4*)&xv[12] = *(const float4*)&smem[t2 * 256 + hh + 12];
#pragma unroll
                    for (int u = 0; u < 16; ++u) h1[t2] = fmaf(xv[u], wA[u], h1[t2]);
#pragma unroll
                    for (int u = 0; u < 16; ++u) h3[t2] = fmaf(xv[u], wB[u], h3[t2]);
                }
                // prefetch next even chunk
#pragma unroll
                for (int u = 0; u < 16; ++u) {
                    wA[u] = wg[(size_t)(hN + u) * I_DIM + j];
                    wB[u] = wu[(size_t)(hN + u) * I_DIM + j];
                }
                // FMA odd chunk
#pragma unroll
                for (int t2 = 0; t2 < 16; ++t2) {
                    float xv[16];
                    *(float4*)&xv[0]  = *(const float4*)&smem[t2 * 256 + hh + 16];
                    *(float4*)&xv[4]  = *(const float4*)&smem[t2 * 256 + hh + 20];
                    *(float4*)&xv[8]  = *(const float4*)&smem[t2 * 256 + hh + 24];
                    *(float4*)&xv[12] = *(const float4*)&smem[t2 * 256 + hh + 28];
#pragma unroll
                    for (int u = 0; u < 16; ++u) h1[t2] = fmaf(xv[u], wC[u], h1[t2]);
#pragma unroll
                    for (int u = 0; u < 16; ++u) h3[t2] = fmaf(xv[u], wD[u], h3[t2]);
                }
            }
        }
        __syncthreads();
#pragma unroll
        for (int t2 = 0; t2 < 16; ++t2) {
            float v1 = h1[t2];
            smem[t2 * 256 + j] = v1 / (1.f + __expf(-v1)) * h3[t2];
        }
        __syncthreads();

        // ---- down projection, flattened (hblk, i-chunk) with ping-pong ----
        // c = hblk*16 + ichunk; identical (hblk outer, ascending i) accumulation.
        float acc[16];
        float vA[16], vB[16];
#pragma unroll
        for (int u = 0; u < 16; ++u) vA[u] = wd[(size_t)u * H + j];   // c = 0
#pragma unroll 1
        for (int c = 0; c < 64; c += 2) {
            const int i0  = (c & 15) * 16;
            const int hb0 = c >> 4;
            const int c1 = c + 1;
            const int i1  = (c1 & 15) * 16;
            const int hb1 = c1 >> 4;
            int c2 = c + 2; if (c2 >= 64) c2 = 0;   // clamp, values unused
            const int i2c = (c2 & 15) * 16;
            const int hb2 = c2 >> 4;

            if ((c & 15) == 0) {
#pragma unroll
                for (int t2 = 0; t2 < 16; ++t2) acc[t2] = 0.f;
            }
            // prefetch c+1
#pragma unroll
            for (int u = 0; u < 16; ++u)
                vB[u] = wd[(size_t)(i1 + u) * H + hb1 * 256 + j];
            // FMA c (vA)
#pragma unroll
            for (int t2 = 0; t2 < 16; ++t2) {
                float av[16];
                *(float4*)&av[0]  = *(const float4*)&smem[t2 * 256 + i0];
                *(float4*)&av[4]  = *(const float4*)&smem[t2 * 256 + i0 + 4];
                *(float4*)&av[8]  = *(const float4*)&smem[t2 * 256 + i0 + 8];
                *(float4*)&av[12] = *(const float4*)&smem[t2 * 256 + i0 + 12];
#pragma unroll
                for (int u = 0; u < 16; ++u) acc[t2] = fmaf(av[u], vA[u], acc[t2]);
            }
            // prefetch c+2
#pragma unroll
            for (int u = 0; u < 16; ++u)
                vA[u] = wd[(size_t)(i2c + u) * H + hb2 * 256 + j];
            // FMA c+1 (vB)
#pragma unroll
            for (int t2 = 0; t2 < 16; ++t2) {
                float av[16];
                *(float4*)&av[0]  = *(const float4*)&smem[t2 * 256 + i1];
                *(float4*)&av[4]  = *(const float4*)&smem[t2 * 256 + i1 + 4];
                *(float4*)&av[8]  = *(const float4*)&smem[t2 * 256 + i1 + 8];
                *(float4*)&av[12] = *(const float4*)&smem[t2 * 256 + i1 + 12];
#pragma unroll
                for (int u = 0; u < 16; ++u) acc[t2] = fmaf(av[u], vB[u], acc[t2]);
            }
            // epilogue once per hblk (c1 = 15, 31, 47, 63)
            if ((c1 & 15) == 15) {
#pragma unroll
                for (int t2 = 0; t2 < 16; ++t2) {
                    if (t2 < nn)
                        atomicAdd(&out[(size_t)stok[t2] * H + hb0 * 256 + j],
                                  swt_s[t2] * acc[t2]);
                }
            }
        }
        if (p == 0) break;
        __syncthreads();   // protect stok/swt_s & smem before next pass
    }
}

extern "C" void kernel_launch(void* const* d_in, const int* in_sizes, int n_in,
                              void* d_out, int out_size, void* d_ws, size_t ws_size,
                              hipStream_t stream) {
    const float* x      = (const float*)d_in[0];  // [1,1,T,H]
    const float* gate_w = (const float*)d_in[1];  // [E,H]
    const float* e_bias = (const float*)d_in[2];  // [E]
    const float* w_gate = (const float*)d_in[3];  // [E,H,I]
    const float* w_up   = (const float*)d_in[4];  // [E,H,I]
    const float* w_down = (const float*)d_in[5];  // [E,I,H]
    const float* swg    = (const float*)d_in[6];  // [H,I]
    const float* swu    = (const float*)d_in[7];  // [H,I]
    const float* swd    = (const float*)d_in[8];  // [I,H]
    float* out = (float*)d_out;

    float* wsf = (float*)d_ws;
    float* logits = wsf;                         // 65536 floats
    int*   cnt    = (int*)(wsf + 65536);         // 256 ints
    int*   tok    = (int*)(wsf + 65792);         // E*CAP ints
    float* wt     = wsf + 65792 + E * CAP;       // E*CAP floats

    k1_logits_shared<<<T, 256, 0, stream>>>(x, gate_w, swg, swu, swd,
                                            logits, cnt, out);
    k2_route<<<T, 64, 0, stream>>>(logits, e_bias, cnt, tok, wt);
    k3_experts<<<2 * E, 256, 0, stream>>>(
        x, w_gate, w_up, w_down, cnt, tok, wt, out);
}